// Round 5
// baseline (242.474 us; speedup 1.0000x reference)
//
#include <hip/hip_runtime.h>

#define BB 4
#define CIN 32
#define COUT 32
#define TT 48
#define NN 2000
#define EE 16000
#define BT (BB*TT)
#define PADCOL 24576   // padded CSR capacity (16000 + 2000*3 = 22000 max)

// ---- build: counts, scan, rowptr, degree terms, weight prep -------------

__global__ __launch_bounds__(1024) void k_build(
        const int* __restrict__ ei,
        const float* __restrict__ w1, const float* __restrict__ gw,
        const float* __restrict__ gb, const float* __restrict__ w2,
        const float* __restrict__ cb2,
        int* __restrict__ rowptr, float* __restrict__ dinv2,
        float* __restrict__ dinvg, int* __restrict__ fillptr,
        int* __restrict__ col, float* __restrict__ wedge,
        float* __restrict__ w1t, float* __restrict__ w2c,
        float* __restrict__ biasE) {
    __shared__ int   cnt[2048];
    __shared__ int   buf[2048];
    __shared__ float sw2t[3072];   // [k][co][c] transposed w2
    __shared__ float sgw[1024];
    __shared__ float sbk[96];      // per-k composed gcn_b bias
    int t = threadIdx.x;

    // 0. stage weights; write w1t (transpose) directly
    for (int i = t; i < 3072; i += 1024) {
        int c = i & 31, r = i >> 5;
        int co = r & 31, k = r >> 5;           // i = (k*32+co)*32 + c
        sw2t[i] = w2[c * 96 + co * 3 + k];
        w1t[i]  = w1[c * 96 + co * 3 + k];
    }
    sgw[t] = gw[t];
    cnt[t] = 0; cnt[t + 1024] = 0;
    __syncthreads();

    // 1. count in-degrees (LDS atomics)
    for (int e = t; e < EE; e += 1024) atomicAdd(&cnt[ei[EE + e]], 1);
    __syncthreads();

    // 2. inclusive scan over PADDED counts (rows padded to multiple of 4)
    for (int i = t; i < 2048; i += 1024)
        buf[i] = (i < NN) ? ((cnt[i] + 3) & ~3) : 0;
    __syncthreads();
    for (int s = 1; s < 2048; s <<= 1) {
        int i0 = t, i1 = t + 1024;
        int a0 = buf[i0] + ((i0 >= s) ? buf[i0 - s] : 0);
        int a1 = buf[i1] + ((i1 >= s) ? buf[i1 - s] : 0);
        __syncthreads();
        buf[i0] = a0; buf[i1] = a1;
        __syncthreads();
    }

    // 3. rowptr + degree terms + global fill pointers
    for (int i = t; i < 2048; i += 1024) {
        if (i < NN) {
            rowptr[i + 1] = buf[i];
            float deg = (float)(cnt[i] + 1);
            dinvg[i] = rsqrtf(deg);
            dinv2[i] = 1.0f / deg;
            fillptr[i] = buf[i] - ((cnt[i] + 3) & ~3);  // padded row start
        }
    }
    if (t == 0) rowptr[0] = 0;

    // 4. zero padded col/wedge (P <= PADCOL)
    int P = buf[NN - 1];
    __syncthreads();
    for (int i = t; i < P; i += 1024) { col[i] = 0; wedge[i] = 0.f; }

    // 5. compose w2c[k][cm][c] = sum_co gw[cm][co] * w2t[k][co][c]  (all LDS)
    for (int i = t; i < 3072; i += 1024) {
        int c = i & 31, r = i >> 5;
        int cm = r & 31, k = r >> 5;
        float acc = 0.f;
#pragma unroll
        for (int co = 0; co < 32; co++)
            acc += sgw[cm * 32 + co] * sw2t[(k * 32 + co) * 32 + c];
        w2c[i] = acc;
    }
    // 6. per-k gcn_b bias, then fold b2 into 3 t-classes:
    //    class0 (t=0):      b2 + bk1 + bk2
    //    class1 (interior): b2 + bk0 + bk1 + bk2
    //    class2 (t=47):     b2 + bk0 + bk1
    for (int i = t; i < 96; i += 1024) {
        int k = i >> 5, c = i & 31;
        float acc = 0.f;
#pragma unroll
        for (int co = 0; co < 32; co++)
            acc += gb[co] * sw2t[(k * 32 + co) * 32 + c];
        sbk[i] = acc;
    }
    __syncthreads();
    for (int i = t; i < 96; i += 1024) {
        int cls = i >> 5, c = i & 31;
        float v = cb2[c] + sbk[32 + c];          // b2 + bk1 always
        if (cls != 0) v += sbk[c];               // + bk0 unless t==0
        if (cls != 2) v += sbk[64 + c];          // + bk2 unless t==47
        biasE[i] = v;
    }
}

// ---- edge fill: parallel across CUs (device-scope atomics) --------------

__global__ void k_fill(const int* __restrict__ ei, int* __restrict__ fillptr,
                       const float* __restrict__ dinvg,
                       int* __restrict__ col, float* __restrict__ wedge) {
    int e = blockIdx.x * blockDim.x + threadIdx.x;
    if (e < EE) {
        int s = ei[e], d = ei[EE + e];
        int pos = atomicAdd(fillptr + d, 1);
        col[pos]   = s;
        wedge[pos] = dinvg[s] * dinvg[d];
    }
}

// ---- conv1: temporal conv + relu -> hbuf BUNDLED [gb][n][gsub][c] -------
// R5: software-pipelined taps. R4 counters: VALUBusy 29.7% x 61us = 18us
// (= the FMA floor) but 43us of exposed load-wait from phase-aligned
// load->FMA alternation. Now tap R's 32 loads issue BEFORE tap M's 2048-cyc
// FMA block, so only the initial L+M load wait is exposed. Boundary taps:
// clamped address (always valid), wave-uniform FMA skip. ~115 VGPR
// (32 acc + 2x32 taps); plain launch_bounds(256), no min-wave cap.

__global__ __launch_bounds__(256) void k_conv1(const float* __restrict__ x,
                                               const float* __restrict__ w1t,
                                               const float* __restrict__ b1,
                                               float* __restrict__ hbuf) {
    // 1536 blocks: xcd = bid&7 owns t in [xcd*6, xcd*6+6) for each b
    int bid = blockIdx.x;
    int xcd = bid & 7;
    int i   = bid >> 3;              // 0..191
    int nch = i & 7;                 // 8 chunks of 256 nodes
    int r   = i >> 3;                // 0..23
    int tloc = r % 6, b = r / 6;
    int t = xcd * 6 + tloc;
    int n = nch * 256 + threadIdx.x;
    if (n >= NN) return;
    int g = b * TT + t;
    int gb = g >> 3, gsub = g & 7;

    float ha[COUT];
#pragma unroll
    for (int c = 0; c < COUT; c++) ha[c] = b1[c];

    const float* xbase = x + ((size_t)b * CIN * TT) * NN + n;
    bool hasL = (t > 0), hasR = (t < TT - 1);
    const float* pL = xbase + (size_t)(hasL ? t - 1 : 0) * NN;   // clamped: always valid
    const float* pM = xbase + (size_t)t * NN;
    const float* pR = xbase + (size_t)(hasR ? t + 1 : 0) * NN;

    float xa[CIN], xm[CIN];
    // taps L and M both in flight
#pragma unroll
    for (int ci = 0; ci < CIN; ci++) xa[ci] = pL[(size_t)ci * TT * NN];
#pragma unroll
    for (int ci = 0; ci < CIN; ci++) xm[ci] = pM[(size_t)ci * TT * NN];
    __builtin_amdgcn_sched_barrier(0);

    if (hasL) {
        const float* wp = w1t;                    // k=0
#pragma unroll
        for (int ci = 0; ci < CIN; ci++) {
#pragma unroll
            for (int c = 0; c < COUT; c++) ha[c] += xa[ci] * wp[ci * COUT + c];
        }
    }
    __builtin_amdgcn_sched_barrier(0);

    // tap R loads issue here; latency hides under tap M's FMA block below
#pragma unroll
    for (int ci = 0; ci < CIN; ci++) xa[ci] = pR[(size_t)ci * TT * NN];
    __builtin_amdgcn_sched_barrier(0);

    {
        const float* wp = w1t + 1024;             // k=1
#pragma unroll
        for (int ci = 0; ci < CIN; ci++) {
#pragma unroll
            for (int c = 0; c < COUT; c++) ha[c] += xm[ci] * wp[ci * COUT + c];
        }
    }
    __builtin_amdgcn_sched_barrier(0);

    if (hasR) {
        const float* wp = w1t + 2048;             // k=2
#pragma unroll
        for (int ci = 0; ci < CIN; ci++) {
#pragma unroll
            for (int c = 0; c < COUT; c++) ha[c] += xa[ci] * wp[ci * COUT + c];
        }
    }

    float4* pa = (float4*)(hbuf + (((size_t)gb * NN + n) * 8 + gsub) * 32);
#pragma unroll
    for (int q = 0; q < 8; q++)
        pa[q] = make_float4(fmaxf(ha[4*q], 0.f), fmaxf(ha[4*q+1], 0.f),
                            fmaxf(ha[4*q+2], 0.f), fmaxf(ha[4*q+3], 0.f));
}

// ---- GCN aggregate, graph-bundled (unchanged: out of top-5) -------------

__global__ __launch_bounds__(256) void k_agg(const float* __restrict__ hbuf,
                                             const int* __restrict__ rowptr,
                                             const int* __restrict__ col,
                                             const float* __restrict__ wedge,
                                             const float* __restrict__ dinv2,
                                             float* __restrict__ gbuf) {
    // 12000 blocks: 8 xcd-slots x 3 bundle-rows x 500 node-quads
    int bid = blockIdx.x;
    int xcd = bid & 7;
    int q   = bid >> 3;
    int gbr = q / 500;
    int nch = q % 500;
    int gb  = gbr * 8 + xcd;
    int wid  = threadIdx.x >> 6;
    int lane = threadIdx.x & 63;
    int gsub = lane >> 3;
    int cq   = lane & 7;
    int n    = nch * 4 + wid;

    const float* xg = hbuf + (size_t)gb * NN * 256;
    size_t loff = (size_t)gsub * 32 + cq * 4;

    float4 self = *(const float4*)(xg + (size_t)n * 256 + loff);
    float dv = dinv2[n];
    float4 acc = make_float4(dv * self.x, dv * self.y, dv * self.z, dv * self.w);

    int j  = rowptr[n];
    int je = rowptr[n + 1];
    for (; j < je; j += 4) {
        int4   cc = *(const int4*)(col + j);
        float4 ww = *(const float4*)(wedge + j);
        float4 v0 = *(const float4*)(xg + (size_t)cc.x * 256 + loff);
        float4 v1 = *(const float4*)(xg + (size_t)cc.y * 256 + loff);
        float4 v2 = *(const float4*)(xg + (size_t)cc.z * 256 + loff);
        float4 v3 = *(const float4*)(xg + (size_t)cc.w * 256 + loff);
        acc.x += ww.x*v0.x + ww.y*v1.x + ww.z*v2.x + ww.w*v3.x;
        acc.y += ww.x*v0.y + ww.y*v1.y + ww.z*v2.y + ww.w*v3.y;
        acc.z += ww.x*v0.z + ww.y*v1.z + ww.z*v2.z + ww.w*v3.z;
        acc.w += ww.x*v0.w + ww.y*v1.w + ww.z*v2.w + ww.w*v3.w;
    }

    int g = gb * 8 + gsub;
    *(float4*)(gbuf + ((size_t)g * NN + n) * 32 + cq * 4) = acc;
}

// ---- conv2: PROVEN one-output-per-thread structure (36 VGPR, no spill)
// + XCD t-locality swizzle: grp = b*48+t. Bias pre-folded into biasE.

__global__ __launch_bounds__(256) void k_conv2(const float* __restrict__ gbuf,
                                               const float* __restrict__ w2c,
                                               const float* __restrict__ biasE,
                                               float* __restrict__ out) {
    int bid  = blockIdx.x;
    int xcd  = bid & 7;
    int slot = bid >> 3;                 // 0..191
    int grp  = xcd * 24 + (slot >> 3);   // 0..191 = b*48 + t
    int nch  = slot & 7;
    int b = grp / TT;
    int t = grp % TT;
    int n = nch * 256 + threadIdx.x;
    if (n >= NN) return;

    float o[COUT];
#pragma unroll
    for (int c = 0; c < COUT; c++) o[c] = 0.f;

    for (int k = 0; k < 3; k++) {
        int tt = t + k - 1;
        if (tt < 0 || tt >= TT) continue;
        const float4* gp = (const float4*)(gbuf + (((size_t)(b * TT + tt)) * NN + n) * CIN);
        const float* wp = w2c + k * CIN * COUT;
        float gv[CIN];
#pragma unroll
        for (int qq = 0; qq < 8; qq++) {
            float4 v = gp[qq];
            gv[4*qq] = v.x; gv[4*qq+1] = v.y; gv[4*qq+2] = v.z; gv[4*qq+3] = v.w;
        }
#pragma unroll
        for (int cm = 0; cm < CIN; cm++) {
#pragma unroll
            for (int c = 0; c < COUT; c++) o[c] += gv[cm] * wp[cm * COUT + c];
        }
    }

    int cls = (t == 0) ? 0 : ((t == TT - 1) ? 2 : 1);
    const float* bp = biasE + cls * 32;
#pragma unroll
    for (int c = 0; c < COUT; c++)
        out[(((size_t)b * COUT + c) * TT + t) * NN + n] = o[c] + bp[c];
}

// ---- launch -------------------------------------------------------------

extern "C" void kernel_launch(void* const* d_in, const int* in_sizes, int n_in,
                              void* d_out, int out_size, void* d_ws, size_t ws_size,
                              hipStream_t stream) {
    const float* x     = (const float*)d_in[0];
    const int*   ei    = (const int*)d_in[1];
    const float* w1    = (const float*)d_in[2];
    const float* b1    = (const float*)d_in[3];
    const float* gcn_w = (const float*)d_in[4];
    const float* gcn_b = (const float*)d_in[5];
    const float* w2    = (const float*)d_in[6];
    const float* b2    = (const float*)d_in[7];
    float* out = (float*)d_out;

    const size_t XWB = (size_t)BT * NN * COUT * sizeof(float);  // 49.152 MB
    char* w = (char*)d_ws;
    float* hbuf    = (float*)w;  w += XWB;   // bundled [gb][n][gsub][c]
    float* gbuf    = (float*)w;  w += XWB;   // standard [g][n][c]
    int*   rowptr  = (int*)w;    w += 8192;
    float* dinv2   = (float*)w;  w += 8192;
    float* dinvg   = (float*)w;  w += 8192;
    int*   fillptr = (int*)w;    w += 8192;
    int*   col     = (int*)w;    w += PADCOL * sizeof(int);
    float* wedge   = (float*)w;  w += PADCOL * sizeof(float);
    float* w1t     = (float*)w;  w += 3072 * sizeof(float);
    float* w2c     = (float*)w;  w += 3072 * sizeof(float);
    float* biasE   = (float*)w;  w += 96 * sizeof(float);

    k_build<<<dim3(1), dim3(1024), 0, stream>>>(ei, w1, gcn_w, gcn_b, w2, b2,
                                                rowptr, dinv2, dinvg, fillptr,
                                                col, wedge, w1t, w2c, biasE);
    k_fill <<<dim3((EE + 255) / 256), dim3(256), 0, stream>>>(ei, fillptr, dinvg, col, wedge);
    k_conv1<<<dim3(1536), dim3(256), 0, stream>>>(x, w1t, b1, hbuf);
    k_agg  <<<dim3(12000), dim3(256), 0, stream>>>(hbuf, rowptr, col, wedge, dinv2, gbuf);
    k_conv2<<<dim3(1536), dim3(256), 0, stream>>>(gbuf, w2c, biasE, out);
}

// Round 6
// 233.892 us; speedup vs baseline: 1.0367x; 1.0367x over previous
//
#include <hip/hip_runtime.h>

#define BB 4
#define CIN 32
#define COUT 32
#define TT 48
#define NN 2000
#define EE 16000
#define BT (BB*TT)
#define PADCOL 24576   // padded CSR capacity (16000 + 2000*3 = 22000 max)

// ---- zero padded CSR arrays (extracted from single-block k_build) -------

__global__ __launch_bounds__(256) void k_zero(int* __restrict__ col,
                                              float* __restrict__ wedge) {
    int i = blockIdx.x * 256 + threadIdx.x;
    if (i < PADCOL) { col[i] = 0; wedge[i] = 0.f; }
}

// ---- build: counts, scan, rowptr, degree terms, weight prep -------------

__global__ __launch_bounds__(1024) void k_build(
        const int* __restrict__ ei,
        const float* __restrict__ w1, const float* __restrict__ gw,
        const float* __restrict__ gb, const float* __restrict__ w2,
        const float* __restrict__ cb2,
        int* __restrict__ rowptr, float* __restrict__ dinv2,
        float* __restrict__ dinvg, int* __restrict__ fillptr,
        float* __restrict__ w1t, float* __restrict__ w2c,
        float* __restrict__ biasE) {
    __shared__ int   cnt[2048];
    __shared__ int   buf[2048];
    __shared__ float sw2t[3072];   // [k][co][c] transposed w2
    __shared__ float sgw[1024];
    __shared__ float sbk[96];      // per-k composed gcn_b bias
    int t = threadIdx.x;

    // 0. stage weights; write w1t (transpose) directly
    for (int i = t; i < 3072; i += 1024) {
        int c = i & 31, r = i >> 5;
        int co = r & 31, k = r >> 5;           // i = (k*32+co)*32 + c
        sw2t[i] = w2[c * 96 + co * 3 + k];
        w1t[i]  = w1[c * 96 + co * 3 + k];
    }
    sgw[t] = gw[t];
    cnt[t] = 0; cnt[t + 1024] = 0;
    __syncthreads();

    // 1. count in-degrees (LDS atomics)
    for (int e = t; e < EE; e += 1024) atomicAdd(&cnt[ei[EE + e]], 1);
    __syncthreads();

    // 2. inclusive scan over PADDED counts (rows padded to multiple of 4)
    for (int i = t; i < 2048; i += 1024)
        buf[i] = (i < NN) ? ((cnt[i] + 3) & ~3) : 0;
    __syncthreads();
    for (int s = 1; s < 2048; s <<= 1) {
        int i0 = t, i1 = t + 1024;
        int a0 = buf[i0] + ((i0 >= s) ? buf[i0 - s] : 0);
        int a1 = buf[i1] + ((i1 >= s) ? buf[i1 - s] : 0);
        __syncthreads();
        buf[i0] = a0; buf[i1] = a1;
        __syncthreads();
    }

    // 3. rowptr + degree terms + global fill pointers
    for (int i = t; i < 2048; i += 1024) {
        if (i < NN) {
            rowptr[i + 1] = buf[i];
            float deg = (float)(cnt[i] + 1);
            dinvg[i] = rsqrtf(deg);
            dinv2[i] = 1.0f / deg;
            fillptr[i] = buf[i] - ((cnt[i] + 3) & ~3);  // padded row start
        }
    }
    if (t == 0) rowptr[0] = 0;

    // 4. (col/wedge zeroing moved to k_zero — ran in parallel earlier)

    // 5. compose w2c[k][cm][c] = sum_co gw[cm][co] * w2t[k][co][c]  (all LDS)
    for (int i = t; i < 3072; i += 1024) {
        int c = i & 31, r = i >> 5;
        int cm = r & 31, k = r >> 5;
        float acc = 0.f;
#pragma unroll
        for (int co = 0; co < 32; co++)
            acc += sgw[cm * 32 + co] * sw2t[(k * 32 + co) * 32 + c];
        w2c[i] = acc;
    }
    // 6. per-k gcn_b bias, then fold b2 into 3 t-classes:
    //    class0 (t=0):      b2 + bk1 + bk2
    //    class1 (interior): b2 + bk0 + bk1 + bk2
    //    class2 (t=47):     b2 + bk0 + bk1
    for (int i = t; i < 96; i += 1024) {
        int k = i >> 5, c = i & 31;
        float acc = 0.f;
#pragma unroll
        for (int co = 0; co < 32; co++)
            acc += gb[co] * sw2t[(k * 32 + co) * 32 + c];
        sbk[i] = acc;
    }
    __syncthreads();
    for (int i = t; i < 96; i += 1024) {
        int cls = i >> 5, c = i & 31;
        float v = cb2[c] + sbk[32 + c];          // b2 + bk1 always
        if (cls != 0) v += sbk[c];               // + bk0 unless t==0
        if (cls != 2) v += sbk[64 + c];          // + bk2 unless t==47
        biasE[i] = v;
    }
}

// ---- edge fill: parallel across CUs (device-scope atomics) --------------

__global__ void k_fill(const int* __restrict__ ei, int* __restrict__ fillptr,
                       const float* __restrict__ dinvg,
                       int* __restrict__ col, float* __restrict__ wedge) {
    int e = blockIdx.x * blockDim.x + threadIdx.x;
    if (e < EE) {
        int s = ei[e], d = ei[EE + e];
        int pos = atomicAdd(fillptr + d, 1);
        col[pos]   = s;
        wedge[pos] = dinvg[s] * dinvg[d];
    }
}

// ---- conv1: temporal conv + relu -> hbuf BUNDLED [gb][n][gsub][c] -------
// R5 software-pipelined taps (kept): tap R's 32 loads issue BEFORE tap M's
// FMA block; only the initial L+M wait is exposed. 80 VGPR -> 4 waves/SIMD
// (VGPR bins step at 64/128: deeper pipelining would cross the 128 cliff).

__global__ __launch_bounds__(256) void k_conv1(const float* __restrict__ x,
                                               const float* __restrict__ w1t,
                                               const float* __restrict__ b1,
                                               float* __restrict__ hbuf) {
    // 1536 blocks: xcd = bid&7 owns t in [xcd*6, xcd*6+6) for each b
    int bid = blockIdx.x;
    int xcd = bid & 7;
    int i   = bid >> 3;              // 0..191
    int nch = i & 7;                 // 8 chunks of 256 nodes
    int r   = i >> 3;                // 0..23
    int tloc = r % 6, b = r / 6;
    int t = xcd * 6 + tloc;
    int n = nch * 256 + threadIdx.x;
    if (n >= NN) return;
    int g = b * TT + t;
    int gb = g >> 3, gsub = g & 7;

    float ha[COUT];
#pragma unroll
    for (int c = 0; c < COUT; c++) ha[c] = b1[c];

    const float* xbase = x + ((size_t)b * CIN * TT) * NN + n;
    bool hasL = (t > 0), hasR = (t < TT - 1);
    const float* pL = xbase + (size_t)(hasL ? t - 1 : 0) * NN;   // clamped: always valid
    const float* pM = xbase + (size_t)t * NN;
    const float* pR = xbase + (size_t)(hasR ? t + 1 : 0) * NN;

    float xa[CIN], xm[CIN];
    // taps L and M both in flight
#pragma unroll
    for (int ci = 0; ci < CIN; ci++) xa[ci] = pL[(size_t)ci * TT * NN];
#pragma unroll
    for (int ci = 0; ci < CIN; ci++) xm[ci] = pM[(size_t)ci * TT * NN];
    __builtin_amdgcn_sched_barrier(0);

    if (hasL) {
        const float* wp = w1t;                    // k=0
#pragma unroll
        for (int ci = 0; ci < CIN; ci++) {
#pragma unroll
            for (int c = 0; c < COUT; c++) ha[c] += xa[ci] * wp[ci * COUT + c];
        }
    }
    __builtin_amdgcn_sched_barrier(0);

    // tap R loads issue here; latency hides under tap M's FMA block below
#pragma unroll
    for (int ci = 0; ci < CIN; ci++) xa[ci] = pR[(size_t)ci * TT * NN];
    __builtin_amdgcn_sched_barrier(0);

    {
        const float* wp = w1t + 1024;             // k=1
#pragma unroll
        for (int ci = 0; ci < CIN; ci++) {
#pragma unroll
            for (int c = 0; c < COUT; c++) ha[c] += xm[ci] * wp[ci * COUT + c];
        }
    }
    __builtin_amdgcn_sched_barrier(0);

    if (hasR) {
        const float* wp = w1t + 2048;             // k=2
#pragma unroll
        for (int ci = 0; ci < CIN; ci++) {
#pragma unroll
            for (int c = 0; c < COUT; c++) ha[c] += xa[ci] * wp[ci * COUT + c];
        }
    }

    float4* pa = (float4*)(hbuf + (((size_t)gb * NN + n) * 8 + gsub) * 32);
#pragma unroll
    for (int q = 0; q < 8; q++)
        pa[q] = make_float4(fmaxf(ha[4*q], 0.f), fmaxf(ha[4*q+1], 0.f),
                            fmaxf(ha[4*q+2], 0.f), fmaxf(ha[4*q+3], 0.f));
}

// ---- GCN aggregate, graph-bundled (unchanged) ---------------------------

__global__ __launch_bounds__(256) void k_agg(const float* __restrict__ hbuf,
                                             const int* __restrict__ rowptr,
                                             const int* __restrict__ col,
                                             const float* __restrict__ wedge,
                                             const float* __restrict__ dinv2,
                                             float* __restrict__ gbuf) {
    // 12000 blocks: 8 xcd-slots x 3 bundle-rows x 500 node-quads
    int bid = blockIdx.x;
    int xcd = bid & 7;
    int q   = bid >> 3;
    int gbr = q / 500;
    int nch = q % 500;
    int gb  = gbr * 8 + xcd;
    int wid  = threadIdx.x >> 6;
    int lane = threadIdx.x & 63;
    int gsub = lane >> 3;
    int cq   = lane & 7;
    int n    = nch * 4 + wid;

    const float* xg = hbuf + (size_t)gb * NN * 256;
    size_t loff = (size_t)gsub * 32 + cq * 4;

    float4 self = *(const float4*)(xg + (size_t)n * 256 + loff);
    float dv = dinv2[n];
    float4 acc = make_float4(dv * self.x, dv * self.y, dv * self.z, dv * self.w);

    int j  = rowptr[n];
    int je = rowptr[n + 1];
    for (; j < je; j += 4) {
        int4   cc = *(const int4*)(col + j);
        float4 ww = *(const float4*)(wedge + j);
        float4 v0 = *(const float4*)(xg + (size_t)cc.x * 256 + loff);
        float4 v1 = *(const float4*)(xg + (size_t)cc.y * 256 + loff);
        float4 v2 = *(const float4*)(xg + (size_t)cc.z * 256 + loff);
        float4 v3 = *(const float4*)(xg + (size_t)cc.w * 256 + loff);
        acc.x += ww.x*v0.x + ww.y*v1.x + ww.z*v2.x + ww.w*v3.x;
        acc.y += ww.x*v0.y + ww.y*v1.y + ww.z*v2.y + ww.w*v3.y;
        acc.z += ww.x*v0.z + ww.y*v1.z + ww.z*v2.z + ww.w*v3.z;
        acc.w += ww.x*v0.w + ww.y*v1.w + ww.z*v2.w + ww.w*v3.w;
    }

    int g = gb * 8 + gsub;
    *(float4*)(gbuf + ((size_t)g * NN + n) * 32 + cq * 4) = acc;
}

// ---- conv2: one-output-per-thread + R5-style tap pipeline ---------------
// Loads of taps L,M issue up front; tap R's loads hide under FMA(M).
// 32 acc + 64 tap buf ~= 110 VGPR (< 128 bin edge). XCD t-locality
// swizzle kept (grp = b*48+t). Bias pre-folded into biasE.

#define LD32(GV, GP) { \
    _Pragma("unroll") \
    for (int q_ = 0; q_ < 8; q_++) { \
        float4 v_ = (GP)[q_]; \
        GV[4*q_] = v_.x; GV[4*q_+1] = v_.y; GV[4*q_+2] = v_.z; GV[4*q_+3] = v_.w; } }

#define FMA32(ACC, GV, WP) { \
    _Pragma("unroll") \
    for (int cm_ = 0; cm_ < 32; cm_++) { \
        float g_ = GV[cm_]; \
        _Pragma("unroll") \
        for (int c_ = 0; c_ < 32; c_++) ACC[c_] += g_ * (WP)[cm_ * 32 + c_]; } }

__global__ __launch_bounds__(256) void k_conv2(const float* __restrict__ gbuf,
                                               const float* __restrict__ w2c,
                                               const float* __restrict__ biasE,
                                               float* __restrict__ out) {
    int bid  = blockIdx.x;
    int xcd  = bid & 7;
    int slot = bid >> 3;                 // 0..191
    int grp  = xcd * 24 + (slot >> 3);   // 0..191 = b*48 + t
    int nch  = slot & 7;
    int b = grp / TT;
    int t = grp % TT;
    int n = nch * 256 + threadIdx.x;
    if (n >= NN) return;

    bool hasL = (t > 0), hasR = (t < TT - 1);
    const float4* pL = (const float4*)(gbuf + (((size_t)(b * TT + (hasL ? t - 1 : 0))) * NN + n) * CIN);
    const float4* pM = (const float4*)(gbuf + (((size_t)(b * TT + t)) * NN + n) * CIN);
    const float4* pR = (const float4*)(gbuf + (((size_t)(b * TT + (hasR ? t + 1 : 0))) * NN + n) * CIN);

    float o[COUT];
#pragma unroll
    for (int c = 0; c < COUT; c++) o[c] = 0.f;

    float ga[CIN], gm[CIN];
    LD32(ga, pL);                        // tap L in flight
    LD32(gm, pM);                        // tap M in flight
    __builtin_amdgcn_sched_barrier(0);

    if (hasL) { FMA32(o, ga, w2c); }     // k=0
    __builtin_amdgcn_sched_barrier(0);

    LD32(ga, pR);                        // tap R hides under FMA(M)
    __builtin_amdgcn_sched_barrier(0);

    FMA32(o, gm, w2c + 1024);            // k=1
    __builtin_amdgcn_sched_barrier(0);

    if (hasR) { FMA32(o, ga, w2c + 2048); }  // k=2

    int cls = (t == 0) ? 0 : ((t == TT - 1) ? 2 : 1);
    const float* bp = biasE + cls * 32;
#pragma unroll
    for (int c = 0; c < COUT; c++)
        out[(((size_t)b * COUT + c) * TT + t) * NN + n] = o[c] + bp[c];
}

// ---- launch -------------------------------------------------------------

extern "C" void kernel_launch(void* const* d_in, const int* in_sizes, int n_in,
                              void* d_out, int out_size, void* d_ws, size_t ws_size,
                              hipStream_t stream) {
    const float* x     = (const float*)d_in[0];
    const int*   ei    = (const int*)d_in[1];
    const float* w1    = (const float*)d_in[2];
    const float* b1    = (const float*)d_in[3];
    const float* gcn_w = (const float*)d_in[4];
    const float* gcn_b = (const float*)d_in[5];
    const float* w2    = (const float*)d_in[6];
    const float* b2    = (const float*)d_in[7];
    float* out = (float*)d_out;

    const size_t XWB = (size_t)BT * NN * COUT * sizeof(float);  // 49.152 MB
    char* w = (char*)d_ws;
    float* hbuf    = (float*)w;  w += XWB;   // bundled [gb][n][gsub][c]
    float* gbuf    = (float*)w;  w += XWB;   // standard [g][n][c]
    int*   rowptr  = (int*)w;    w += 8192;
    float* dinv2   = (float*)w;  w += 8192;
    float* dinvg   = (float*)w;  w += 8192;
    int*   fillptr = (int*)w;    w += 8192;
    int*   col     = (int*)w;    w += PADCOL * sizeof(int);
    float* wedge   = (float*)w;  w += PADCOL * sizeof(float);
    float* w1t     = (float*)w;  w += 3072 * sizeof(float);
    float* w2c     = (float*)w;  w += 3072 * sizeof(float);
    float* biasE   = (float*)w;  w += 96 * sizeof(float);

    k_zero <<<dim3((PADCOL + 255) / 256), dim3(256), 0, stream>>>(col, wedge);
    k_build<<<dim3(1), dim3(1024), 0, stream>>>(ei, w1, gcn_w, gcn_b, w2, b2,
                                                rowptr, dinv2, dinvg, fillptr,
                                                w1t, w2c, biasE);
    k_fill <<<dim3((EE + 255) / 256), dim3(256), 0, stream>>>(ei, fillptr, dinvg, col, wedge);
    k_conv1<<<dim3(1536), dim3(256), 0, stream>>>(x, w1t, b1, hbuf);
    k_agg  <<<dim3(12000), dim3(256), 0, stream>>>(hbuf, rowptr, col, wedge, dinv2, gbuf);
    k_conv2<<<dim3(1536), dim3(256), 0, stream>>>(gbuf, w2c, biasE, out);
}